// Round 9
// baseline (378.499 us; speedup 1.0000x reference)
//
#include <hip/hip_runtime.h>
#include <hip/hip_bf16.h>
#include <math.h>

// Problem shape (fixed): B=8, L=2048, D=1024, n=16, d=64
#define BATCH 8
#define SEQL  2048
#define DIM   1024
#define NHEAD 16
#define MROWS (BATCH * SEQL)   // 16384

typedef _Float16 f16;
typedef _Float16 f16x8 __attribute__((ext_vector_type(8)));
typedef _Float16 f16x4 __attribute__((ext_vector_type(4)));
typedef _Float16 f16x2 __attribute__((ext_vector_type(2)));
typedef float f32x4 __attribute__((ext_vector_type(4)));

typedef const __attribute__((address_space(1))) void* gp_t;
typedef __attribute__((address_space(3))) void* lp_t;
#define GLL(src, dst) __builtin_amdgcn_global_load_lds((gp_t)(src), (lp_t)(dst), 16, 0, 0)

// ---------------------------------------------------------------------------
// fp32 -> f16 convert, 8 elems/thread
__global__ __launch_bounds__(256) void cvt_f32_f16(const float* __restrict__ in,
                                                   f16* __restrict__ out, int n8)
{
    const int i = blockIdx.x * 256 + threadIdx.x;
    if (i >= n8) return;
    const float4* p = (const float4*)in + (size_t)i * 2;
    const float4 a = p[0], b = p[1];
    f16x8 v;
    v[0] = (f16)a.x; v[1] = (f16)a.y; v[2] = (f16)a.z; v[3] = (f16)a.w;
    v[4] = (f16)b.x; v[5] = (f16)b.y; v[6] = (f16)b.z; v[7] = (f16)b.w;
    *(f16x8*)(out + (size_t)i * 8) = v;
}

// ---------------------------------------------------------------------------
// 256x256-tile 8-phase f16 MFMA GEMM (T3+T4 counted vmcnt, T2 swizzle via
// inverse-swizzled global source, T5 setprio). See R7 notes.
// MODE 0: fp32 C0, N=1024.  MODE 1: N=2048 split: col<1024 -> f16 k (C0),
// col>=1024 -> 8*sigmoid(+bias) f16 g2 (C1)  [x8 folded out of the scan chain].
template<int MODE>
__global__ __launch_bounds__(512, 2) void gemm8(const f16* __restrict__ A,
                                                const f16* __restrict__ Bw,
                                                const float* __restrict__ bias,
                                                void* __restrict__ C0,
                                                void* __restrict__ C1)
{
    constexpr int K   = 1024;
    constexpr int NTI = MODE ? 8 : 4;   // N/256
    constexpr int NKT = 16;             // K/64
    __shared__ f16 lds[2][2][256 * 64]; // [buf][A=0/B=1], 128 KiB

    const int tid = threadIdx.x;
    const int w = tid >> 6, l = tid & 63;
    const int wm = w >> 2, wn = w & 3;
    const int lrow = l & 15;
    const int l7 = l & 7, lk = l >> 4;

    // bijective XCD swizzle (grid % 8 == 0)
    const int cpx = gridDim.x >> 3;
    const int lt  = (blockIdx.x & 7) * cpx + (blockIdx.x >> 3);
    const int bm  = (lt / NTI) * 256;
    const int bn  = (lt % NTI) * 256;

    // staging geometry: 512 threads x 2 x 16B = one 128x64 half-tile
    const int srl   = tid >> 3;                 // 0..63 row within 64-row round
    const int sg    = tid & 7;                  // LDS granule slot
    const int scolx = (sg ^ (srl & 7)) * 8;     // inverse-swizzled source col

    // swizzled ds-read granule offsets (elems) for ks=0/1
    const int g0 = ((lk) ^ l7) * 8;
    const int g1 = ((4 + lk) ^ l7) * 8;

#define STAGE(t, m, P, rowbase, h)                                                       \
    do {                                                                                 \
        const int _rf0 = (h) * 128 + srl;                                                \
        GLL((P) + (size_t)((rowbase) + _rf0) * K + (t) * 64 + scolx,                     \
            &lds[(t) & 1][m][_rf0 * 64 + sg * 8]);                                       \
        const int _rf1 = _rf0 + 64;                                                      \
        GLL((P) + (size_t)((rowbase) + _rf1) * K + (t) * 64 + scolx,                     \
            &lds[(t) & 1][m][_rf1 * 64 + sg * 8]);                                       \
    } while (0)

    f32x4 acc[8][4];
    #pragma unroll
    for (int mi = 0; mi < 8; ++mi)
        #pragma unroll
        for (int ni = 0; ni < 4; ++ni) acc[mi][ni] = (f32x4){0.f, 0.f, 0.f, 0.f};

    f16x8 bf[4][2];

#define PHASE(p, cur, STG, LOAD_B)                                                       \
    do {                                                                                 \
        const f16* _ab = &lds[cur][0][0];                                                \
        const int _ar = (wm * 128 + (2 * (p)) * 16 + lrow) * 64;                         \
        f16x8 a00 = *(const f16x8*)(_ab + _ar + g0);                                     \
        f16x8 a01 = *(const f16x8*)(_ab + _ar + g1);                                     \
        f16x8 a10 = *(const f16x8*)(_ab + _ar + 1024 + g0);                              \
        f16x8 a11 = *(const f16x8*)(_ab + _ar + 1024 + g1);                              \
        if (LOAD_B) {                                                                    \
            const f16* _bb = &lds[cur][1][0];                                            \
            _Pragma("unroll")                                                            \
            for (int ni = 0; ni < 4; ++ni) {                                             \
                const int _br = (wn * 64 + ni * 16 + lrow) * 64;                         \
                bf[ni][0] = *(const f16x8*)(_bb + _br + g0);                             \
                bf[ni][1] = *(const f16x8*)(_bb + _br + g1);                             \
            }                                                                            \
        }                                                                                \
        STG;                                                                             \
        __builtin_amdgcn_s_barrier();                                                    \
        asm volatile("s_waitcnt lgkmcnt(0)" ::: "memory");                               \
        __builtin_amdgcn_sched_barrier(0);                                               \
        __builtin_amdgcn_s_setprio(1);                                                   \
        _Pragma("unroll")                                                                \
        for (int ni = 0; ni < 4; ++ni) {                                                 \
            acc[2*(p)][ni]   = __builtin_amdgcn_mfma_f32_16x16x32_f16(a00, bf[ni][0], acc[2*(p)][ni], 0, 0, 0);   \
            acc[2*(p)][ni]   = __builtin_amdgcn_mfma_f32_16x16x32_f16(a01, bf[ni][1], acc[2*(p)][ni], 0, 0, 0);   \
            acc[2*(p)+1][ni] = __builtin_amdgcn_mfma_f32_16x16x32_f16(a10, bf[ni][0], acc[2*(p)+1][ni], 0, 0, 0); \
            acc[2*(p)+1][ni] = __builtin_amdgcn_mfma_f32_16x16x32_f16(a11, bf[ni][1], acc[2*(p)+1][ni], 0, 0, 0); \
        }                                                                                \
        __builtin_amdgcn_s_setprio(0);                                                   \
    } while (0)

    // prologue: A(0),B(0),B(1); wait A(0)+B(0) (first 8 of 12 loads)
    STAGE(0, 0, A, bm, 0);  STAGE(0, 0, A, bm, 1);
    STAGE(0, 1, Bw, bn, 0); STAGE(0, 1, Bw, bn, 1);
    STAGE(1, 1, Bw, bn, 0); STAGE(1, 1, Bw, bn, 1);
    asm volatile("s_waitcnt vmcnt(4)" ::: "memory");
    __builtin_amdgcn_s_barrier();

    for (int t = 0; t < NKT; ++t) {
        const int cur = t & 1;
        PHASE(0, cur, { if (t + 1 < NKT) STAGE(t + 1, 0, A, bm, 0); }, 1);
        __builtin_amdgcn_s_barrier();
        PHASE(1, cur, { if (t + 1 < NKT) STAGE(t + 1, 0, A, bm, 1); }, 0);
        __builtin_amdgcn_s_barrier();
        PHASE(2, cur, { if (t + 2 < NKT) STAGE(t + 2, 1, Bw, bn, 0); }, 0);
        __builtin_amdgcn_s_barrier();
        PHASE(3, cur, { if (t + 2 < NKT) STAGE(t + 2, 1, Bw, bn, 1); }, 0);
        if (t + 2 < NKT)      asm volatile("s_waitcnt vmcnt(4)" ::: "memory");
        else if (t + 1 < NKT) asm volatile("s_waitcnt vmcnt(0)" ::: "memory");
        __builtin_amdgcn_s_barrier();
    }
#undef PHASE
#undef STAGE

    // epilogue: C/D layout col = l&15, row = (l>>4)*4 + r
    const int orow = (l >> 4) * 4;
    const int ocol = l & 15;
    #pragma unroll
    for (int mi = 0; mi < 8; ++mi) {
        #pragma unroll
        for (int ni = 0; ni < 4; ++ni) {
            const int col  = bn + wn * 64 + ni * 16 + ocol;
            const int row0 = bm + wm * 128 + mi * 16 + orow;
            #pragma unroll
            for (int r = 0; r < 4; ++r) {
                float v = acc[mi][ni][r];
                if (MODE == 0) {
                    ((float*)C0)[(size_t)(row0 + r) * DIM + col] = v;
                } else {
                    if (col < DIM) {
                        ((f16*)C0)[(size_t)(row0 + r) * DIM + col] = (f16)v;     // k
                    } else {
                        v += bias[col - DIM];
                        v = 8.f / (1.f + __expf(-v));        // g2 = 8*sigmoid
                        ((f16*)C1)[(size_t)(row0 + r) * DIM + (col - DIM)] = (f16)v;
                    }
                }
            }
        }
    }
}

// ---------------------------------------------------------------------------
// DPP cross-lane add (VALU latency). CTRL compile-time.
template<int CTRL>
__device__ __forceinline__ float dpp_add_f(float s) {
    int t = __builtin_amdgcn_update_dpp(0, __float_as_int(s), CTRL, 0xF, 0xF, true);
    return s + __int_as_float(t);
}

__device__ __forceinline__ float sumsq4(f16x2 a, f16x2 b) {
#if __has_builtin(__builtin_amdgcn_fdot2)
    return __builtin_amdgcn_fdot2(a, a, __builtin_amdgcn_fdot2(b, b, 0.f, false), false);
#else
    return (float)a[0] * (float)a[0] + (float)a[1] * (float)a[1]
         + (float)b[0] * (float)b[0] + (float)b[1] * (float)b[1];
#endif
}

#define PF 16   // prefetch depth (steps); divides SEQL

// Scan, 2-way sequence-group interleaved: 16 waves, each handles 8 sequences
// as two independent 4-seq groups (A = heads oct*8+row, B = +4). The two
// chains are independent -> scheduler overlaps them, hiding ~half the
// dependent-chain latency. Layout per group: 4 seqs per wave (16-lane rows),
// 4 dims/lane (f16x4), packed-f16 state, 4-hop row-local DPP butterfly.
// g is pre-scaled by 8 in the GEMM epilogue: h' = (h*g2)*rsq(S+6.4e-7) + k
// (bit-equivalent to rsq(S/64+1e-8)*8 used before).
__global__ __launch_bounds__(64) void scan_kernel(const f16* __restrict__ Kv,
                                                  const f16* __restrict__ Gv,
                                                  f16* __restrict__ Ov)
{
    const int w = blockIdx.x;     // 0..15: batch = w>>1, head-octet = w&1
    const int l = threadIdx.x;

    const size_t baseA = (size_t)(w >> 1) * (SEQL * DIM)
                       + (size_t)((w & 1) * 512 + (l >> 4) * 64 + (l & 15) * 4);
    // group B = heads +4 -> +256 elems

    f16x2 hA0 = (f16x2){(f16)0.f, (f16)0.f}, hA1 = hA0;
    f16x2 hB0 = hA0, hB1 = hA0;

    f16x4 kbA[PF], gbA[PF], kbB[PF], gbB[PF];
    #pragma unroll
    for (int u = 0; u < PF; ++u) {
        const size_t o = baseA + (size_t)u * DIM;
        kbA[u] = *(const f16x4*)(Kv + o);
        gbA[u] = *(const f16x4*)(Gv + o);
        kbB[u] = *(const f16x4*)(Kv + o + 256);
        gbB[u] = *(const f16x4*)(Gv + o + 256);
    }

    size_t off = baseA;

    #define STEP_PAIR(kA, gA, kB, gB)                                                  \
        do {                                                                           \
            const f16x2 kA0 = __builtin_shufflevector((kA), (kA), 0, 1);               \
            const f16x2 kA1 = __builtin_shufflevector((kA), (kA), 2, 3);               \
            const f16x2 gA0 = __builtin_shufflevector((gA), (gA), 0, 1);               \
            const f16x2 gA1 = __builtin_shufflevector((gA), (gA), 2, 3);               \
            const f16x2 kB0 = __builtin_shufflevector((kB), (kB), 0, 1);               \
            const f16x2 kB1 = __builtin_shufflevector((kB), (kB), 2, 3);               \
            const f16x2 gB0 = __builtin_shufflevector((gB), (gB), 0, 1);               \
            const f16x2 gB1 = __builtin_shufflevector((gB), (gB), 2, 3);               \
            const f16x2 uA0 = hA0 * gA0, uA1 = hA1 * gA1;                              \
            const f16x2 uB0 = hB0 * gB0, uB1 = hB1 * gB1;                              \
            float sA = sumsq4(hA0, hA1);                                               \
            float sB = sumsq4(hB0, hB1);                                               \
            sA = dpp_add_f<0xB1>(sA);  sB = dpp_add_f<0xB1>(sB);                       \
            sA = dpp_add_f<0x4E>(sA);  sB = dpp_add_f<0x4E>(sB);                       \
            sA = dpp_add_f<0x141>(sA); sB = dpp_add_f<0x141>(sB);                      \
            sA = dpp_add_f<0x140>(sA); sB = dpp_add_f<0x140>(sB);                      \
            const float invA = __builtin_amdgcn_rsqf(sA + 6.4e-7f);                    \
            const float invB = __builtin_amdgcn_rsqf(sB + 6.4e-7f);                    \
            const f16 iA = (f16)invA; const f16x2 ivA = (f16x2){iA, iA};               \
            const f16 iB = (f16)invB; const f16x2 ivB = (f16x2){iB, iB};               \
            hA0 = uA0 * ivA + kA0; hA1 = uA1 * ivA + kA1;                              \
            hB0 = uB0 * ivB + kB0; hB1 = uB1 * ivB + kB1;                              \
            f16x4 oA; oA[0] = hA0[0]; oA[1] = hA0[1]; oA[2] = hA1[0]; oA[3] = hA1[1];  \
            f16x4 oB; oB[0] = hB0[0]; oB[1] = hB0[1]; oB[2] = hB1[0]; oB[3] = hB1[1];  \
            *(f16x4*)(Ov + off) = oA;                                                  \
            *(f16x4*)(Ov + off + 256) = oB;                                            \
            off += DIM;                                                                \
        } while (0)

    for (int t0 = 0; t0 + PF < SEQL; t0 += PF) {
        #pragma unroll
        for (int u = 0; u < PF; ++u) {
            const f16x4 kA = kbA[u], gA = gbA[u], kB = kbB[u], gB = gbB[u];
            const size_t poff = off + (size_t)PF * DIM;   // refill PF ahead
            kbA[u] = *(const f16x4*)(Kv + poff);
            gbA[u] = *(const f16x4*)(Gv + poff);
            kbB[u] = *(const f16x4*)(Kv + poff + 256);
            gbB[u] = *(const f16x4*)(Gv + poff + 256);
            STEP_PAIR(kA, gA, kB, gB);
        }
    }
    #pragma unroll
    for (int u = 0; u < PF; ++u) {
        const f16x4 kA = kbA[u], gA = gbA[u], kB = kbB[u], gB = gbB[u];
        STEP_PAIR(kA, gA, kB, gB);
    }
    #undef STEP_PAIR
}

// ---------------------------------------------------------------------------
extern "C" void kernel_launch(void* const* d_in, const int* in_sizes, int n_in,
                              void* d_out, int out_size, void* d_ws, size_t ws_size,
                              hipStream_t stream) {
    const float* x    = (const float*)d_in[0];
    const float* Wk   = (const float*)d_in[1];
    const float* Wkg  = (const float*)d_in[2];
    const float* bkg  = (const float*)d_in[3];
    const float* Wout = (const float*)d_in[4];
    float* out = (float*)d_out;

    // workspace (f16): xh/Kh/Gh 32MB each + Wcat 4MB + Wout 2MB = 102MB
    f16* xh    = (f16*)d_ws;                         // [M, D]; scan output reuses it
    f16* Kh    = xh    + (size_t)MROWS * DIM;
    f16* Gh    = Kh    + (size_t)MROWS * DIM;
    f16* Wcat  = Gh    + (size_t)MROWS * DIM;        // [2048, 1024]: Wk ; Wkg
    f16* Wouth = Wcat  + (size_t)2 * DIM * DIM;

    const int nx8 = MROWS * DIM / 8;
    const int nw8 = DIM * DIM / 8;
    cvt_f32_f16<<<dim3(nx8 / 256), dim3(256), 0, stream>>>(x, xh, nx8);
    cvt_f32_f16<<<dim3(nw8 / 256), dim3(256), 0, stream>>>(Wk, Wcat, nw8);
    cvt_f32_f16<<<dim3(nw8 / 256), dim3(256), 0, stream>>>(Wkg, Wcat + (size_t)DIM * DIM, nw8);
    cvt_f32_f16<<<dim3(nw8 / 256), dim3(256), 0, stream>>>(Wout, Wouth, nw8);

    // fused k|g GEMM: M=16384, N=2048 -> 64 x 8 = 512 blocks
    gemm8<1><<<dim3(512), dim3(512), 0, stream>>>(xh, Wcat, bkg, Kh, Gh);
    // scan: o -> xh (16 waves, 8 seqs each, 2-way interleaved)
    scan_kernel<<<dim3(16), dim3(64), 0, stream>>>(Kh, Gh, xh);
    // out = o @ Wout.T: 64 x 4 = 256 blocks
    gemm8<0><<<dim3(256), dim3(512), 0, stream>>>(xh, Wouth, nullptr, out, nullptr);
}

// Round 10
// 310.219 us; speedup vs baseline: 1.2201x; 1.2201x over previous
//
#include <hip/hip_runtime.h>
#include <hip/hip_bf16.h>
#include <math.h>

// Problem shape (fixed): B=8, L=2048, D=1024, n=16, d=64
#define BATCH 8
#define SEQL  2048
#define DIM   1024
#define NHEAD 16
#define MROWS (BATCH * SEQL)   // 16384

typedef _Float16 f16;
typedef _Float16 f16x8 __attribute__((ext_vector_type(8)));
typedef _Float16 f16x4 __attribute__((ext_vector_type(4)));
typedef _Float16 f16x2 __attribute__((ext_vector_type(2)));
typedef float f32x4 __attribute__((ext_vector_type(4)));

typedef const __attribute__((address_space(1))) void* gp_t;
typedef __attribute__((address_space(3))) void* lp_t;
#define GLL(src, dst) __builtin_amdgcn_global_load_lds((gp_t)(src), (lp_t)(dst), 16, 0, 0)

// ---------------------------------------------------------------------------
// fp32 -> f16 convert, 8 elems/thread
__global__ __launch_bounds__(256) void cvt_f32_f16(const float* __restrict__ in,
                                                   f16* __restrict__ out, int n8)
{
    const int i = blockIdx.x * 256 + threadIdx.x;
    if (i >= n8) return;
    const float4* p = (const float4*)in + (size_t)i * 2;
    const float4 a = p[0], b = p[1];
    f16x8 v;
    v[0] = (f16)a.x; v[1] = (f16)a.y; v[2] = (f16)a.z; v[3] = (f16)a.w;
    v[4] = (f16)b.x; v[5] = (f16)b.y; v[6] = (f16)b.z; v[7] = (f16)b.w;
    *(f16x8*)(out + (size_t)i * 8) = v;
}

// ---------------------------------------------------------------------------
// 256x256-tile 8-phase f16 MFMA GEMM (T3+T4 counted vmcnt, T2 swizzle via
// inverse-swizzled global source, T5 setprio). See R7 notes.
// MODE 0: fp32 C0, N=1024.  MODE 1: N=2048 split: col<1024 -> f16 k (C0),
// col>=1024 -> 8*sigmoid(+bias) f16 g2 (C1)  [x8 folded out of the scan chain].
template<int MODE>
__global__ __launch_bounds__(512, 2) void gemm8(const f16* __restrict__ A,
                                                const f16* __restrict__ Bw,
                                                const float* __restrict__ bias,
                                                void* __restrict__ C0,
                                                void* __restrict__ C1)
{
    constexpr int K   = 1024;
    constexpr int NTI = MODE ? 8 : 4;   // N/256
    constexpr int NKT = 16;             // K/64
    __shared__ f16 lds[2][2][256 * 64]; // [buf][A=0/B=1], 128 KiB

    const int tid = threadIdx.x;
    const int w = tid >> 6, l = tid & 63;
    const int wm = w >> 2, wn = w & 3;
    const int lrow = l & 15;
    const int l7 = l & 7, lk = l >> 4;

    // bijective XCD swizzle (grid % 8 == 0)
    const int cpx = gridDim.x >> 3;
    const int lt  = (blockIdx.x & 7) * cpx + (blockIdx.x >> 3);
    const int bm  = (lt / NTI) * 256;
    const int bn  = (lt % NTI) * 256;

    // staging geometry: 512 threads x 2 x 16B = one 128x64 half-tile
    const int srl   = tid >> 3;                 // 0..63 row within 64-row round
    const int sg    = tid & 7;                  // LDS granule slot
    const int scolx = (sg ^ (srl & 7)) * 8;     // inverse-swizzled source col

    // swizzled ds-read granule offsets (elems) for ks=0/1
    const int g0 = ((lk) ^ l7) * 8;
    const int g1 = ((4 + lk) ^ l7) * 8;

#define STAGE(t, m, P, rowbase, h)                                                       \
    do {                                                                                 \
        const int _rf0 = (h) * 128 + srl;                                                \
        GLL((P) + (size_t)((rowbase) + _rf0) * K + (t) * 64 + scolx,                     \
            &lds[(t) & 1][m][_rf0 * 64 + sg * 8]);                                       \
        const int _rf1 = _rf0 + 64;                                                      \
        GLL((P) + (size_t)((rowbase) + _rf1) * K + (t) * 64 + scolx,                     \
            &lds[(t) & 1][m][_rf1 * 64 + sg * 8]);                                       \
    } while (0)

    f32x4 acc[8][4];
    #pragma unroll
    for (int mi = 0; mi < 8; ++mi)
        #pragma unroll
        for (int ni = 0; ni < 4; ++ni) acc[mi][ni] = (f32x4){0.f, 0.f, 0.f, 0.f};

    f16x8 bf[4][2];

#define PHASE(p, cur, STG, LOAD_B)                                                       \
    do {                                                                                 \
        const f16* _ab = &lds[cur][0][0];                                                \
        const int _ar = (wm * 128 + (2 * (p)) * 16 + lrow) * 64;                         \
        f16x8 a00 = *(const f16x8*)(_ab + _ar + g0);                                     \
        f16x8 a01 = *(const f16x8*)(_ab + _ar + g1);                                     \
        f16x8 a10 = *(const f16x8*)(_ab + _ar + 1024 + g0);                              \
        f16x8 a11 = *(const f16x8*)(_ab + _ar + 1024 + g1);                              \
        if (LOAD_B) {                                                                    \
            const f16* _bb = &lds[cur][1][0];                                            \
            _Pragma("unroll")                                                            \
            for (int ni = 0; ni < 4; ++ni) {                                             \
                const int _br = (wn * 64 + ni * 16 + lrow) * 64;                         \
                bf[ni][0] = *(const f16x8*)(_bb + _br + g0);                             \
                bf[ni][1] = *(const f16x8*)(_bb + _br + g1);                             \
            }                                                                            \
        }                                                                                \
        STG;                                                                             \
        __builtin_amdgcn_s_barrier();                                                    \
        asm volatile("s_waitcnt lgkmcnt(0)" ::: "memory");                               \
        __builtin_amdgcn_sched_barrier(0);                                               \
        __builtin_amdgcn_s_setprio(1);                                                   \
        _Pragma("unroll")                                                                \
        for (int ni = 0; ni < 4; ++ni) {                                                 \
            acc[2*(p)][ni]   = __builtin_amdgcn_mfma_f32_16x16x32_f16(a00, bf[ni][0], acc[2*(p)][ni], 0, 0, 0);   \
            acc[2*(p)][ni]   = __builtin_amdgcn_mfma_f32_16x16x32_f16(a01, bf[ni][1], acc[2*(p)][ni], 0, 0, 0);   \
            acc[2*(p)+1][ni] = __builtin_amdgcn_mfma_f32_16x16x32_f16(a10, bf[ni][0], acc[2*(p)+1][ni], 0, 0, 0); \
            acc[2*(p)+1][ni] = __builtin_amdgcn_mfma_f32_16x16x32_f16(a11, bf[ni][1], acc[2*(p)+1][ni], 0, 0, 0); \
        }                                                                                \
        __builtin_amdgcn_s_setprio(0);                                                   \
    } while (0)

    // prologue: A(0),B(0),B(1); wait A(0)+B(0) (first 8 of 12 loads)
    STAGE(0, 0, A, bm, 0);  STAGE(0, 0, A, bm, 1);
    STAGE(0, 1, Bw, bn, 0); STAGE(0, 1, Bw, bn, 1);
    STAGE(1, 1, Bw, bn, 0); STAGE(1, 1, Bw, bn, 1);
    asm volatile("s_waitcnt vmcnt(4)" ::: "memory");
    __builtin_amdgcn_s_barrier();

    for (int t = 0; t < NKT; ++t) {
        const int cur = t & 1;
        PHASE(0, cur, { if (t + 1 < NKT) STAGE(t + 1, 0, A, bm, 0); }, 1);
        __builtin_amdgcn_s_barrier();
        PHASE(1, cur, { if (t + 1 < NKT) STAGE(t + 1, 0, A, bm, 1); }, 0);
        __builtin_amdgcn_s_barrier();
        PHASE(2, cur, { if (t + 2 < NKT) STAGE(t + 2, 1, Bw, bn, 0); }, 0);
        __builtin_amdgcn_s_barrier();
        PHASE(3, cur, { if (t + 2 < NKT) STAGE(t + 2, 1, Bw, bn, 1); }, 0);
        if (t + 2 < NKT)      asm volatile("s_waitcnt vmcnt(4)" ::: "memory");
        else if (t + 1 < NKT) asm volatile("s_waitcnt vmcnt(0)" ::: "memory");
        __builtin_amdgcn_s_barrier();
    }
#undef PHASE
#undef STAGE

    // epilogue: C/D layout col = l&15, row = (l>>4)*4 + r
    const int orow = (l >> 4) * 4;
    const int ocol = l & 15;
    #pragma unroll
    for (int mi = 0; mi < 8; ++mi) {
        #pragma unroll
        for (int ni = 0; ni < 4; ++ni) {
            const int col  = bn + wn * 64 + ni * 16 + ocol;
            const int row0 = bm + wm * 128 + mi * 16 + orow;
            #pragma unroll
            for (int r = 0; r < 4; ++r) {
                float v = acc[mi][ni][r];
                if (MODE == 0) {
                    ((float*)C0)[(size_t)(row0 + r) * DIM + col] = v;
                } else {
                    if (col < DIM) {
                        ((f16*)C0)[(size_t)(row0 + r) * DIM + col] = (f16)v;     // k
                    } else {
                        v += bias[col - DIM];
                        v = 8.f / (1.f + __expf(-v));        // g2 = 8*sigmoid
                        ((f16*)C1)[(size_t)(row0 + r) * DIM + (col - DIM)] = (f16)v;
                    }
                }
            }
        }
    }
}

// ---------------------------------------------------------------------------
// DPP cross-lane add (VALU latency). CTRL compile-time.
template<int CTRL>
__device__ __forceinline__ float dpp_add_f(float s) {
    int t = __builtin_amdgcn_update_dpp(0, __float_as_int(s), CTRL, 0xF, 0xF, true);
    return s + __int_as_float(t);
}

#define PF 16   // prefetch depth (steps); divides SEQL

// Scan with decoupled norm recurrence. Layout (R8-proven): 32 waves, 4
// sequences/wave (16-lane rows), 4 dims/lane (f16x4), packed-f16 state.
//
// Instead of reducing |h'|^2 AFTER the update (R8: reduce sits between
// h-update and next h-update, ~150cy chain), expand
//   S' = inv^2*Sum(u^2) + 2*inv*Sum(u*k) + Sum(k^2),   u = h*g2
// The per-lane partials a,b,c are computable from h,g,k BEFORE inv is
// known, so the serial spine is just: inv -> 2 fma -> 4 DPP -> fmax -> rsq.
// g2 = 8*sigmoid(.) from the GEMM epilogue; inv = rsq(S) (floored) gives
// h' = h*g/(sqrt(S)/8) + k, matching the reference within f16 tolerance.
// h0 = 0 handled by inv0 = 0: u = 0 exactly -> h1 = k for any finite inv.
__global__ __launch_bounds__(64) void scan_kernel(const f16* __restrict__ Kv,
                                                  const f16* __restrict__ Gv,
                                                  f16* __restrict__ Ov)
{
    const int w = blockIdx.x;     // 0..31
    const int l = threadIdx.x;

    const size_t base = (size_t)(w >> 2) * (SEQL * DIM) + (size_t)((w & 3) * 256 + l * 4);
    f16x2 h01 = (f16x2){(f16)0.f, (f16)0.f};
    f16x2 h23 = (f16x2){(f16)0.f, (f16)0.f};
    float inv = 0.f;              // rsq(S_t); 0 is safe at t=0 (u=0)

    f16x4 kb[PF], gb[PF];
    #pragma unroll
    for (int u = 0; u < PF; ++u) {
        kb[u] = *(const f16x4*)(Kv + base + (size_t)u * DIM);
        gb[u] = *(const f16x4*)(Gv + base + (size_t)u * DIM);
    }

    size_t off = base;

    #define SCAN_STEP(kc, gc)                                                          \
        do {                                                                           \
            const f16x2 k01 = __builtin_shufflevector((kc), (kc), 0, 1);               \
            const f16x2 k23 = __builtin_shufflevector((kc), (kc), 2, 3);               \
            const f16x2 g01 = __builtin_shufflevector((gc), (gc), 0, 1);               \
            const f16x2 g23 = __builtin_shufflevector((gc), (gc), 2, 3);               \
            const f16x2 u01 = h01 * g01;   /* v_pk_mul_f16 */                          \
            const f16x2 u23 = h23 * g23;                                               \
            /* per-lane partials (independent of inv) */                               \
            const float a = __builtin_amdgcn_fdot2(u01, u01,                           \
                              __builtin_amdgcn_fdot2(u23, u23, 0.f, false), false);    \
            const float b = __builtin_amdgcn_fdot2(u01, k01,                           \
                              __builtin_amdgcn_fdot2(u23, k23, 0.f, false), false);    \
            const float c = __builtin_amdgcn_fdot2(k01, k01,                           \
                              __builtin_amdgcn_fdot2(k23, k23, 0.f, false), false);    \
            const float b2 = b + b;                                                    \
            /* h update (off the norm spine) */                                        \
            const f16 ih = (f16)inv;                                                   \
            const f16x2 iv = (f16x2){ih, ih};                                          \
            h01 = u01 * iv + k01;          /* v_pk_fma_f16 */                          \
            h23 = u23 * iv + k23;                                                      \
            f16x4 o;                                                                   \
            o[0] = h01[0]; o[1] = h01[1]; o[2] = h23[0]; o[3] = h23[1];                \
            *(f16x4*)(Ov + off) = o;                                                   \
            /* norm spine: 2 fma -> 4 DPP -> fmax -> rsq */                            \
            float s = fmaf(fmaf(a, inv, b2), inv, c);                                  \
            s = dpp_add_f<0xB1>(s);   /* xor1 */                                       \
            s = dpp_add_f<0x4E>(s);   /* xor2 */                                       \
            s = dpp_add_f<0x141>(s);  /* xor4 */                                       \
            s = dpp_add_f<0x140>(s);  /* xor8 */                                       \
            inv = __builtin_amdgcn_rsqf(fmaxf(s, 6.4e-7f));                            \
            off += DIM;                                                                \
        } while (0)

    for (int t0 = 0; t0 + PF < SEQL; t0 += PF) {
        #pragma unroll
        for (int u = 0; u < PF; ++u) {
            const f16x4 kc = kb[u], gc = gb[u];
            const size_t poff = off + (size_t)PF * DIM;   // refill PF ahead
            kb[u] = *(const f16x4*)(Kv + poff);
            gb[u] = *(const f16x4*)(Gv + poff);
            SCAN_STEP(kc, gc);
        }
    }
    #pragma unroll
    for (int u = 0; u < PF; ++u) {
        const f16x4 kc = kb[u], gc = gb[u];
        SCAN_STEP(kc, gc);
    }
    #undef SCAN_STEP
}

// ---------------------------------------------------------------------------
extern "C" void kernel_launch(void* const* d_in, const int* in_sizes, int n_in,
                              void* d_out, int out_size, void* d_ws, size_t ws_size,
                              hipStream_t stream) {
    const float* x    = (const float*)d_in[0];
    const float* Wk   = (const float*)d_in[1];
    const float* Wkg  = (const float*)d_in[2];
    const float* bkg  = (const float*)d_in[3];
    const float* Wout = (const float*)d_in[4];
    float* out = (float*)d_out;

    // workspace (f16): xh/Kh/Gh 32MB each + Wcat 4MB + Wout 2MB = 102MB
    f16* xh    = (f16*)d_ws;                         // [M, D]; scan output reuses it
    f16* Kh    = xh    + (size_t)MROWS * DIM;
    f16* Gh    = Kh    + (size_t)MROWS * DIM;
    f16* Wcat  = Gh    + (size_t)MROWS * DIM;        // [2048, 1024]: Wk ; Wkg
    f16* Wouth = Wcat  + (size_t)2 * DIM * DIM;

    const int nx8 = MROWS * DIM / 8;
    const int nw8 = DIM * DIM / 8;
    cvt_f32_f16<<<dim3(nx8 / 256), dim3(256), 0, stream>>>(x, xh, nx8);
    cvt_f32_f16<<<dim3(nw8 / 256), dim3(256), 0, stream>>>(Wk, Wcat, nw8);
    cvt_f32_f16<<<dim3(nw8 / 256), dim3(256), 0, stream>>>(Wkg, Wcat + (size_t)DIM * DIM, nw8);
    cvt_f32_f16<<<dim3(nw8 / 256), dim3(256), 0, stream>>>(Wout, Wouth, nw8);

    // fused k|g GEMM: M=16384, N=2048 -> 64 x 8 = 512 blocks
    gemm8<1><<<dim3(512), dim3(512), 0, stream>>>(xh, Wcat, bkg, Kh, Gh);
    // scan: o -> xh (32 waves, 4 seqs each, decoupled norm recurrence)
    scan_kernel<<<dim3(32), dim3(64), 0, stream>>>(Kh, Gh, xh);
    // out = o @ Wout.T: 64 x 4 = 256 blocks
    gemm8<0><<<dim3(256), dim3(512), 0, stream>>>(xh, Wouth, nullptr, out, nullptr);
}